// Round 5
// baseline (142.799 us; speedup 1.0000x reference)
//
#include <hip/hip_runtime.h>

// RelativePositionEncoding, N=1024, C=128, out = 512 MiB f32 write-stream.
// R4 post-mortem: time invariant to inner-loop work => test the structural
// hypothesis. This version mimics fillBufferAligned's shape exactly:
// 256-thread blocks, NO LDS, low VGPR, grid-stride flat stores.
// A tiny prep kernel materializes into device globals:
//   pk[1024]    : packed (residue, token, asym<<16|entity, mask) per token
//   wt2[133][128]: row 0..64  = Wpos[dp] + Wchain[dc=2]   (same-chain merged)
//                  row 65..130 = Wtok[dt] (dt=65 -> oob col 131)
//                  row 131    = Wpos[65]+Wtok[65]+Wchain[5] (cross-chain const)
//                  row 132    = Went
// Main loop: cross-chain (~87%): v=(sdiff + f*went)*mm   (registers only)
//            same-chain:        v=(wt2[dp]+wt2[65+dt'] + f*went)*mm (2 L2 loads)

#define N_TOK  1024
#define C_PAIR 128
#define W_COLS 139

typedef float f32x4 __attribute__((ext_vector_type(4)));
typedef int   i32x4 __attribute__((ext_vector_type(4)));

__device__ f32x4 g_wt2[133 * 32];   // 133 rows x 128 ch (as 32 f32x4)
__device__ i32x4 g_pk[N_TOK];

__global__ __launch_bounds__(256)
void prep_kernel(const int* __restrict__ ri, const int* __restrict__ ti,
                 const int* __restrict__ ai, const int* __restrict__ ei,
                 const float* __restrict__ mask, const float* __restrict__ W) {
    for (int j = threadIdx.x; j < N_TOK; j += blockDim.x) {
        i32x4 p;
        p.x = ri[j];
        p.y = ti[j];
        p.z = (ai[j] << 16) | (ei[j] & 0xffff);
        p.w = __float_as_int(mask[j]);
        g_pk[j] = p;
    }
    float* wt2 = (float*)g_wt2;
    for (int idx = threadIdx.x; idx < 133 * C_PAIR; idx += blockDim.x) {
        int k = idx >> 7;          // row
        int c = idx & 127;         // channel
        const float* Wc = W + c * W_COLS;
        float v;
        if (k < 65)        v = Wc[k] + Wc[135];            // Wpos[dp]+Wchain[2]
        else if (k < 131)  v = Wc[k - 65 + 66];            // Wtok[dt]
        else if (k == 131) v = Wc[65] + Wc[131] + Wc[138]; // cross-chain sum
        else               v = Wc[132];                    // Went
        wt2[idx] = v;
    }
}

__global__ __launch_bounds__(256)
void relpos_kernel(float* __restrict__ out) {
    const int total  = N_TOK * N_TOK * 32;       // f32x4 items
    const int stride = gridDim.x * blockDim.x;   // 524,288 -> 64 iters/thread
    int g0 = blockIdx.x * blockDim.x + threadIdx.x;

    const int c4 = g0 & 31;                      // loop-invariant channel slot
    const f32x4 sdiff = g_wt2[131 * 32 + c4];    // cross-chain constant
    const f32x4 went  = g_wt2[132 * 32 + c4];
    f32x4* __restrict__ out4 = (f32x4*)out;

    #pragma unroll 4
    for (int g = g0; g < total; g += stride) {
        int pair = g >> 5;
        int j = pair & (N_TOK - 1);
        int i = pair >> 10;

        i32x4 pi = g_pk[i];                      // broadcast, L1-resident
        i32x4 pj = g_pk[j];

        float mm = __int_as_float(pi.w) * __int_as_float(pj.w);
        float f  = ((pi.z & 0xffff) == (pj.z & 0xffff)) ? 1.0f : 0.0f;

        f32x4 v;
        if ((pi.z >> 16) == (pj.z >> 16)) {      // same chain (~12.5%)
            int dp  = min(max(pj.x - pi.x + 32, 0), 64);
            int dtp = (pi.x == pj.x) ? min(max(pj.y - pi.y + 32, 0), 64) : 65;
            v = g_wt2[dp * 32 + c4] + g_wt2[(65 + dtp) * 32 + c4];  // L2, 512B coalesced
        } else {                                 // cross chain (~87.5%)
            v = sdiff;
        }
        v = (v + f * went) * mm;
        out4[g] = v;                             // wave: 1 KB contiguous
    }
}

extern "C" void kernel_launch(void* const* d_in, const int* in_sizes, int n_in,
                              void* d_out, int out_size, void* d_ws, size_t ws_size,
                              hipStream_t stream) {
    const int*   ri   = (const int*)d_in[0];
    const int*   ti   = (const int*)d_in[1];
    const int*   ai   = (const int*)d_in[2];
    const int*   ei   = (const int*)d_in[3];
    const float* mask = (const float*)d_in[4];
    const float* W    = (const float*)d_in[5];
    float*       out  = (float*)d_out;

    prep_kernel<<<1, 256, 0, stream>>>(ri, ti, ai, ei, mask, W);
    relpos_kernel<<<2048, 256, 0, stream>>>(out);   // fill-like: no LDS, 8 blk/CU
}